// Round 2
// baseline (898.659 us; speedup 1.0000x reference)
//
#include <hip/hip_runtime.h>
#include <cstdint>
#include <cstddef>

#define T_TOK 2048
#define DHID  2048
#define NEXP  8
#define FMOE  1408
#define FSH   2816
#define CAP   5120   // 4096 slots + 8*128 per-expert padding
#define SH_W  (FSH * DHID)          // 5,767,168 elems per shared weight
#define EXP_W (NEXP * FMOE * DHID)  // 23,068,672 elems per expert weight set

typedef short short8 __attribute__((ext_vector_type(8)));
typedef float f32x4  __attribute__((ext_vector_type(4)));

__device__ __forceinline__ float bf2f(short s) {
  unsigned u = ((unsigned)(unsigned short)s) << 16;
  return __builtin_bit_cast(float, u);
}
__device__ __forceinline__ short f2bf(float f) {
  unsigned u = __builtin_bit_cast(unsigned, f);
  u += 0x7fffu + ((u >> 16) & 1u);
  return (short)(u >> 16);
}
__device__ __forceinline__ short8 cvt8(float4 a, float4 b) {
  short8 r;
  r[0]=f2bf(a.x); r[1]=f2bf(a.y); r[2]=f2bf(a.z); r[3]=f2bf(a.w);
  r[4]=f2bf(b.x); r[5]=f2bf(b.y); r[6]=f2bf(b.z); r[7]=f2bf(b.w);
  return r;
}

// async 16B global -> LDS (wave-uniform base + lane*16 semantics; our per-lane
// lds pointers are exactly base + lane*16, matching the HW layout)
__device__ __forceinline__ void gl_lds16(const void* g, void* l) {
  __builtin_amdgcn_global_load_lds(
      (const __attribute__((address_space(1))) void*)g,
      (__attribute__((address_space(3))) void*)l, 16, 0, 0);
}

// ---- fp32 -> bf16 weight conversion, 6 tensors in one dispatch ----
__global__ void k_cvt6(const float* __restrict__ s0, const float* __restrict__ s1,
                       const float* __restrict__ s2, const float* __restrict__ s3,
                       const float* __restrict__ s4, const float* __restrict__ s5,
                       short* __restrict__ d0, short* __restrict__ d1,
                       short* __restrict__ d2, short* __restrict__ d3,
                       short* __restrict__ d4, short* __restrict__ d5)
{
  const float* s; short* d; size_t n;
  switch (blockIdx.y) {
    case 0: s = s0; d = d0; n = SH_W;  break;
    case 1: s = s1; d = d1; n = SH_W;  break;
    case 2: s = s2; d = d2; n = SH_W;  break;
    case 3: s = s3; d = d3; n = EXP_W; break;
    case 4: s = s4; d = d4; n = EXP_W; break;
    default: s = s5; d = d5; n = EXP_W; break;
  }
  size_t i = ((size_t)blockIdx.x * 256 + threadIdx.x) * 8;
  if (i >= n) return;
  float4 f0 = *(const float4*)(s + i);
  float4 f1 = *(const float4*)(s + i + 4);
  *(short8*)(d + i) = cvt8(f0, f1);
}

// ---- gating: fp32 scores, sigmoid, top-2, counts; also write x as bf16 ----
__global__ void k_gate(const float* __restrict__ x, const float* __restrict__ gw,
                       int* __restrict__ top_idx, float* __restrict__ top_w,
                       int* __restrict__ ctrl, short* __restrict__ x16)
{
  int t = blockIdx.x, tid = threadIdx.x;
  const float* xr = x + (size_t)t * DHID + tid * 8;
  float4 v0 = *(const float4*)xr;
  float4 v1 = *(const float4*)(xr + 4);
  *(short8*)(x16 + (size_t)t * DHID + tid * 8) = cvt8(v0, v1);

  float s[NEXP];
  #pragma unroll
  for (int e = 0; e < NEXP; e++) {
    const float* gr = gw + e * DHID + tid * 8;
    float4 g0 = *(const float4*)gr;
    float4 g1 = *(const float4*)(gr + 4);
    s[e] = v0.x*g0.x + v0.y*g0.y + v0.z*g0.z + v0.w*g0.w
         + v1.x*g1.x + v1.y*g1.y + v1.z*g1.z + v1.w*g1.w;
  }
  #pragma unroll
  for (int e = 0; e < NEXP; e++)
    #pragma unroll
    for (int off = 32; off > 0; off >>= 1)
      s[e] += __shfl_xor(s[e], off);

  __shared__ float red[4][NEXP];
  int lane = tid & 63, wave = tid >> 6;
  if (lane == 0)
    for (int e = 0; e < NEXP; e++) red[wave][e] = s[e];
  __syncthreads();

  if (tid == 0) {
    float sc[NEXP];
    for (int e = 0; e < NEXP; e++) {
      float v = red[0][e] + red[1][e] + red[2][e] + red[3][e];
      sc[e] = 1.f / (1.f + __expf(-v));
    }
    int i0 = 0; float s0 = sc[0];
    for (int e = 1; e < NEXP; e++) if (sc[e] > s0) { s0 = sc[e]; i0 = e; }
    int i1 = -1; float s1 = -1e30f;
    for (int e = 0; e < NEXP; e++) if (e != i0 && sc[e] > s1) { s1 = sc[e]; i1 = e; }
    float inv = 2.5f / (s0 + s1 + 1e-20f);
    top_idx[2*t] = i0; top_idx[2*t+1] = i1;
    top_w[2*t] = s0 * inv; top_w[2*t+1] = s1 * inv;
    atomicAdd(&ctrl[i0], 1);
    atomicAdd(&ctrl[i1], 1);
  }
}

// ---- per-expert offsets, 128-row padded regions ----
__global__ void k_offsets(int* __restrict__ ctrl)
{
  if (blockIdx.x == 0 && threadIdx.x == 0) {
    int cum = 0;
    for (int e = 0; e < NEXP; e++) {
      ctrl[16 + e] = cum;
      cum += (ctrl[e] + 127) & ~127;
    }
  }
}

// ---- gather token rows into compact per-expert matrix Xg ----
__global__ void k_gather(const short* __restrict__ x16, const int* __restrict__ top_idx,
                         int* __restrict__ ctrl, int* __restrict__ tok_row,
                         short* __restrict__ Xg)
{
  int t = blockIdx.x, tid = threadIdx.x;
  __shared__ int rows[2];
  if (tid < 2) {
    int e = top_idx[2*t + tid];
    int slot = atomicAdd(&ctrl[8 + e], 1);
    int row = ctrl[16 + e] + slot;
    rows[tid] = row;
    tok_row[2*t + tid] = row;
  }
  __syncthreads();
  uint4 v = *(const uint4*)(x16 + (size_t)t * DHID + tid * 8);
  *(uint4*)(Xg + (size_t)rows[0] * DHID + tid * 8) = v;
  *(uint4*)(Xg + (size_t)rows[1] * DHID + tid * 8) = v;
}

// ---- fused gate/up GEMM + SiLU: H = silu(A Wg^T) * (A Wu^T) ----
// 64(M) x 128(N) tile; A bf16 stride K; Wg/Wu bf16 [N,K] (expert: +e*N*K).
// async global_load_lds staging, m97-style 2-barrier K-loop.
template<bool EXPERT>
__global__ __launch_bounds__(256) void k_guf(
    const short* __restrict__ A, const short* __restrict__ Wg,
    const short* __restrict__ Wu, short* __restrict__ H,
    int N, int K, const int* __restrict__ ctrl)
{
  int m0 = blockIdx.y * 64;
  if (EXPERT) {
    int e = blockIdx.z;
    if (m0 >= ctrl[e]) return;
    m0 += ctrl[16 + e];
    size_t woff = (size_t)e * N * K;
    Wg += woff; Wu += woff;
  }
  int n0 = blockIdx.x * 128;

  __shared__ short Asm[64 * 32];    // 4 KB
  __shared__ short Bgs[128 * 32];   // 8 KB
  __shared__ short Bus[128 * 32];   // 8 KB

  int tid = threadIdx.x;
  int lane = tid & 63, wave = tid >> 6;
  int l15 = lane & 15, q = lane >> 4;
  int wm = (wave >> 1) * 32, wn = (wave & 1) * 64;

  f32x4 z4 = {0.f, 0.f, 0.f, 0.f};
  f32x4 accg[2][4], accu[2][4];
  #pragma unroll
  for (int a = 0; a < 2; a++)
    #pragma unroll
    for (int b = 0; b < 4; b++) { accg[a][b] = z4; accu[a][b] = z4; }

  // chunk c covers LDS row c>>2, k-sub (c&3)*8 elems; lds dest = base + c*16B
  int r = tid >> 2, kc = (tid & 3) * 8;
  const short* Ag  = A  + (size_t)(m0 + r) * K + kc;
  const short* Bg0 = Wg + (size_t)(n0 + r) * K + kc;
  const short* Bg1 = Wg + (size_t)(n0 + 64 + r) * K + kc;
  const short* Bu0 = Wu + (size_t)(n0 + r) * K + kc;
  const short* Bu1 = Wu + (size_t)(n0 + 64 + r) * K + kc;
  short* Asd  = Asm + tid * 8;
  short* Bgd0 = Bgs + tid * 8;
  short* Bgd1 = Bgs + 2048 + tid * 8;
  short* Bud0 = Bus + tid * 8;
  short* Bud1 = Bus + 2048 + tid * 8;

  for (int k0 = 0; k0 < K; k0 += 32) {
    gl_lds16(Ag  + k0, Asd);
    gl_lds16(Bg0 + k0, Bgd0);
    gl_lds16(Bg1 + k0, Bgd1);
    gl_lds16(Bu0 + k0, Bud0);
    gl_lds16(Bu1 + k0, Bud1);
    __syncthreads();   // drains vmcnt -> tiles complete, all waves synced

    short8 af[2], bgf[4], buf_[4];
    #pragma unroll
    for (int mi = 0; mi < 2; mi++)
      af[mi] = *(const short8*)&Asm[(wm + mi * 16 + l15) * 32 + q * 8];
    #pragma unroll
    for (int ni = 0; ni < 4; ni++) {
      bgf[ni]  = *(const short8*)&Bgs[(wn + ni * 16 + l15) * 32 + q * 8];
      buf_[ni] = *(const short8*)&Bus[(wn + ni * 16 + l15) * 32 + q * 8];
    }
    #pragma unroll
    for (int mi = 0; mi < 2; mi++)
      #pragma unroll
      for (int ni = 0; ni < 4; ni++) {
        accg[mi][ni] = __builtin_amdgcn_mfma_f32_16x16x32_bf16(af[mi], bgf[ni],  accg[mi][ni], 0, 0, 0);
        accu[mi][ni] = __builtin_amdgcn_mfma_f32_16x16x32_bf16(af[mi], buf_[ni], accu[mi][ni], 0, 0, 0);
      }
    __syncthreads();   // all reads done before next iter overwrites
  }

  // epilogue: D row = q*4 + reg, col = l15  [measured m89/m91]; h = silu(g)*u
  #pragma unroll
  for (int mi = 0; mi < 2; mi++) {
    #pragma unroll
    for (int rr = 0; rr < 4; rr++) {
      size_t row = (size_t)(m0 + wm + mi * 16 + q * 4 + rr);
      size_t base = row * (size_t)N + n0 + wn + l15;
      #pragma unroll
      for (int ni = 0; ni < 4; ni++) {
        float g = accg[mi][ni][rr];
        float u = accu[mi][ni][rr];
        float h = (g / (1.f + __expf(-g))) * u;
        H[base + ni * 16] = f2bf(h);
      }
    }
  }
}

// ---- down GEMM: C[M,DHID] = H[M,K] @ Wd[DHID,K]^T ----
// 64x128 tile. EXPERT: bf16 out (rout), row-indirect; else fp32 out (d_out).
template<bool EXPERT>
__global__ __launch_bounds__(256) void k_down(
    const short* __restrict__ A, const short* __restrict__ W,
    void* __restrict__ Cv, int N, int K, const int* __restrict__ ctrl)
{
  int m0 = blockIdx.y * 64;
  if (EXPERT) {
    int e = blockIdx.z;
    if (m0 >= ctrl[e]) return;
    m0 += ctrl[16 + e];
    W += (size_t)e * N * K;
  }
  int n0 = blockIdx.x * 128;

  __shared__ short Asm[64 * 32];
  __shared__ short Bsm[128 * 32];

  int tid = threadIdx.x;
  int lane = tid & 63, wave = tid >> 6;
  int l15 = lane & 15, q = lane >> 4;
  int wm = (wave >> 1) * 32, wn = (wave & 1) * 64;

  f32x4 z4 = {0.f, 0.f, 0.f, 0.f};
  f32x4 acc[2][4];
  #pragma unroll
  for (int a = 0; a < 2; a++)
    #pragma unroll
    for (int b = 0; b < 4; b++) acc[a][b] = z4;

  int r = tid >> 2, kc = (tid & 3) * 8;
  const short* Ag = A + (size_t)(m0 + r) * K + kc;
  const short* B0 = W + (size_t)(n0 + r) * K + kc;
  const short* B1 = W + (size_t)(n0 + 64 + r) * K + kc;
  short* Asd = Asm + tid * 8;
  short* Bd0 = Bsm + tid * 8;
  short* Bd1 = Bsm + 2048 + tid * 8;

  for (int k0 = 0; k0 < K; k0 += 32) {
    gl_lds16(Ag + k0, Asd);
    gl_lds16(B0 + k0, Bd0);
    gl_lds16(B1 + k0, Bd1);
    __syncthreads();

    short8 af[2], bf[4];
    #pragma unroll
    for (int mi = 0; mi < 2; mi++)
      af[mi] = *(const short8*)&Asm[(wm + mi * 16 + l15) * 32 + q * 8];
    #pragma unroll
    for (int ni = 0; ni < 4; ni++)
      bf[ni] = *(const short8*)&Bsm[(wn + ni * 16 + l15) * 32 + q * 8];
    #pragma unroll
    for (int mi = 0; mi < 2; mi++)
      #pragma unroll
      for (int ni = 0; ni < 4; ni++)
        acc[mi][ni] = __builtin_amdgcn_mfma_f32_16x16x32_bf16(af[mi], bf[ni], acc[mi][ni], 0, 0, 0);
    __syncthreads();
  }

  #pragma unroll
  for (int mi = 0; mi < 2; mi++) {
    #pragma unroll
    for (int rr = 0; rr < 4; rr++) {
      size_t row = (size_t)(m0 + wm + mi * 16 + q * 4 + rr);
      size_t base = row * (size_t)N + n0 + wn + l15;
      #pragma unroll
      for (int ni = 0; ni < 4; ni++) {
        float v = acc[mi][ni][rr];
        if (EXPERT) ((short*)Cv)[base + ni * 16] = f2bf(v);
        else        ((float*)Cv)[base + ni * 16] = v;
      }
    }
  }
}

// ---- out += w0*routed[row0] + w1*routed[row1] ----
__global__ void k_add(float* __restrict__ out, const short* __restrict__ rout,
                      const int* __restrict__ tok_row, const float* __restrict__ top_w)
{
  int t = blockIdx.x, tid = threadIdx.x;
  int r0 = tok_row[2*t], r1 = tok_row[2*t+1];
  float w0 = top_w[2*t], w1 = top_w[2*t+1];
  size_t c = (size_t)tid * 8;
  short8 a = *(const short8*)(rout + (size_t)r0 * DHID + c);
  short8 b = *(const short8*)(rout + (size_t)r1 * DHID + c);
  float* o = out + (size_t)t * DHID + c;
  float4 o0 = *(float4*)o;
  float4 o1 = *(float4*)(o + 4);
  o0.x += w0*bf2f(a[0]) + w1*bf2f(b[0]);
  o0.y += w0*bf2f(a[1]) + w1*bf2f(b[1]);
  o0.z += w0*bf2f(a[2]) + w1*bf2f(b[2]);
  o0.w += w0*bf2f(a[3]) + w1*bf2f(b[3]);
  o1.x += w0*bf2f(a[4]) + w1*bf2f(b[4]);
  o1.y += w0*bf2f(a[5]) + w1*bf2f(b[5]);
  o1.z += w0*bf2f(a[6]) + w1*bf2f(b[6]);
  o1.w += w0*bf2f(a[7]) + w1*bf2f(b[7]);
  *(float4*)o = o0;
  *(float4*)(o + 4) = o1;
}

extern "C" void kernel_launch(void* const* d_in, const int* in_sizes, int n_in,
                              void* d_out, int out_size, void* d_ws, size_t ws_size,
                              hipStream_t stream)
{
  const float* x   = (const float*)d_in[0];
  const float* gw  = (const float*)d_in[1];
  const float* swg = (const float*)d_in[2];
  const float* swu = (const float*)d_in[3];
  const float* swd = (const float*)d_in[4];
  const float* ewg = (const float*)d_in[5];
  const float* ewu = (const float*)d_in[6];
  const float* ewd = (const float*)d_in[7];
  float* out = (float*)d_out;

  // workspace carve (~238 MB)
  char* p = (char*)d_ws;
  int*   ctrl    = (int*)p;   p += 256;   // [0..7] counts, [8..15] cursor, [16..23] offsets
  int*   top_idx = (int*)p;   p += T_TOK * 2 * sizeof(int);
  float* top_w   = (float*)p; p += T_TOK * 2 * sizeof(float);
  int*   tok_row = (int*)p;   p += T_TOK * 2 * sizeof(int);
  short* x16   = (short*)p;   p += (size_t)T_TOK * DHID * 2;
  short* Xg    = (short*)p;   p += (size_t)CAP * DHID * 2;
  short* swg16 = (short*)p;   p += (size_t)SH_W * 2;
  short* swu16 = (short*)p;   p += (size_t)SH_W * 2;
  short* swd16 = (short*)p;   p += (size_t)SH_W * 2;
  short* ewg16 = (short*)p;   p += (size_t)EXP_W * 2;
  short* ewu16 = (short*)p;   p += (size_t)EXP_W * 2;
  short* ewd16 = (short*)p;   p += (size_t)EXP_W * 2;
  short* hbuf  = (short*)p;   p += (size_t)CAP * FMOE * 2;  // also holds shared h (T_TOK*FSH fits)
  short* rout  = (short*)p;   p += (size_t)CAP * DHID * 2;

  (void)hipMemsetAsync(ctrl, 0, 64, stream);

  k_cvt6<<<dim3(EXP_W / 2048, 6), 256, 0, stream>>>(swg, swu, swd, ewg, ewu, ewd,
                                                    swg16, swu16, swd16, ewg16, ewu16, ewd16);
  k_gate<<<T_TOK, 256, 0, stream>>>(x, gw, top_idx, top_w, ctrl, x16);
  k_offsets<<<1, 64, 0, stream>>>(ctrl);
  k_gather<<<T_TOK, 256, 0, stream>>>(x16, top_idx, ctrl, tok_row, Xg);

  // shared branch: fused g/u+silu -> h, then down -> out (fp32)
  k_guf<false><<<dim3(FSH/128, T_TOK/64, 1), 256, 0, stream>>>(
      x16, swg16, swu16, hbuf, FSH, DHID, nullptr);
  k_down<false><<<dim3(DHID/128, T_TOK/64, 1), 256, 0, stream>>>(
      hbuf, swd16, out, DHID, FSH, nullptr);

  // expert branch: fused g/u+silu -> h, then down -> rout (bf16)
  k_guf<true><<<dim3(FMOE/128, 32, NEXP), 256, 0, stream>>>(
      Xg, ewg16, ewu16, hbuf, FMOE, DHID, ctrl);
  k_down<true><<<dim3(DHID/128, 32, NEXP), 256, 0, stream>>>(
      hbuf, ewd16, rout, DHID, FMOE, ctrl);

  k_add<<<T_TOK, 256, 0, stream>>>(out, rout, tok_row, top_w);
}